// Round 1
// baseline (159.988 us; speedup 1.0000x reference)
//
#include <hip/hip_runtime.h>

// ---------------- problem constants ----------------
#define B_  2
#define N_  8192
#define I_  32
#define E_  128
#define H_  64
#define BN_ (B_*N_)          // 16384
#define NW_ (N_/64)          // 128 u64 words per (b,i) mask row

typedef unsigned long long u64;

// ---------------- module-scope device state (fully rewritten every launch) -----
__device__ float g_pe  [B_*I_*E_];     // pos_embed
__device__ float g_v1  [B_*I_*H_];     // decode hidden bias, initial
__device__ float g_v2  [B_*I_*H_];     // decode hidden bias, refined
__device__ float g_wd1t[E_*H_];        // Wd1 transposed [e][k]
__device__ float g_u   [H_*BN_];       // u[k][p] (4 MB, k-major -> coalesced)
__device__ u64   g_masks[B_*I_*NW_];   // initial masks as bitwords (64 KB)
// folded effective weights (no nonlinearity between LoRA2 and decoder linear1)
__device__ float g_w1eff[H_*3];        // W1 + 0.25*B1@A1          [k][c]
__device__ float g_w2eff[E_*H_];       // W2 + 0.25*B2@A2          [e][j]
__device__ float g_meff [H_*H_];       // W2eff^T @ Wd1^T          [j][k]

// ---------------- jax threefry2x32, key = key(42) = (0,42) ----------------
__device__ __forceinline__ unsigned rotl_(unsigned x, unsigned n){ return (x<<n)|(x>>(32u-n)); }

__device__ void threefry_42(unsigned x0, unsigned x1, unsigned* r0, unsigned* r1){
  const unsigned ks0 = 0u, ks1 = 42u, ks2 = 0x1BD11BDAu ^ 0u ^ 42u;
  x0 += ks0; x1 += ks1;
  x0+=x1; x1=rotl_(x1,13); x1^=x0;
  x0+=x1; x1=rotl_(x1,15); x1^=x0;
  x0+=x1; x1=rotl_(x1,26); x1^=x0;
  x0+=x1; x1=rotl_(x1, 6); x1^=x0;
  x0+=ks1; x1+=ks2+1u;
  x0+=x1; x1=rotl_(x1,17); x1^=x0;
  x0+=x1; x1=rotl_(x1,29); x1^=x0;
  x0+=x1; x1=rotl_(x1,16); x1^=x0;
  x0+=x1; x1=rotl_(x1,24); x1^=x0;
  x0+=ks2; x1+=ks0+2u;
  x0+=x1; x1=rotl_(x1,13); x1^=x0;
  x0+=x1; x1=rotl_(x1,15); x1^=x0;
  x0+=x1; x1=rotl_(x1,26); x1^=x0;
  x0+=x1; x1=rotl_(x1, 6); x1^=x0;
  x0+=ks0; x1+=ks1+3u;
  x0+=x1; x1=rotl_(x1,17); x1^=x0;
  x0+=x1; x1=rotl_(x1,29); x1^=x0;
  x0+=x1; x1=rotl_(x1,16); x1^=x0;
  x0+=x1; x1=rotl_(x1,24); x1^=x0;
  x0+=ks1; x1+=ks2+4u;
  x0+=x1; x1=rotl_(x1,13); x1^=x0;
  x0+=x1; x1=rotl_(x1,15); x1^=x0;
  x0+=x1; x1=rotl_(x1,26); x1^=x0;
  x0+=x1; x1=rotl_(x1, 6); x1^=x0;
  x0+=ks2; x1+=ks0+5u;
  *r0 = x0; *r1 = x1;
}

// element e of jax.random.uniform(key(42), (2,32,32), 1e-20, 1.0)
// PARTITIONABLE threefry (VERIFIED r7): counter (0,e), bits = out0 ^ out1.
__device__ float jax_uniform_2048(int e){
  unsigned o0, o1;
  threefry_42(0u, (unsigned)e, &o0, &o1);
  unsigned bits = o0 ^ o1;
  float u = __uint_as_float((bits >> 9) | 0x3f800000u) - 1.0f;
  u = u + 1e-20f;
  return fmaxf(1e-20f, u);
}

// ---------------- K0: pos_embed + Wd1^T + v1 + folded weights ----------------
// blocks 0..63: one (b,i) row each (pe, v1; block 0 also writes g_wd1t).
// block 64: W1eff, W2eff, Meff = W2eff^T @ Wd1^T.
__global__ void __launch_bounds__(256) prep_kernel(
    const float* __restrict__ pos_coords,
    const float* __restrict__ Wp, const float* __restrict__ bp,
    const float* __restrict__ Wd1,const float* __restrict__ bd1,
    const float* __restrict__ W1, const float* __restrict__ A1,
    const float* __restrict__ B1, const float* __restrict__ W2,
    const float* __restrict__ A2, const float* __restrict__ B2)
{
  __shared__ float t_l [E_*65];      // Wd1^T tile [e][k], pad 65: 33.3 KB
  __shared__ float w2_l[E_*65];      // W2eff tile [e][j] (block 64 only)
  __shared__ float pe_l[E_];
  const int row = blockIdx.x;
  const int tid = threadIdx.x;

  // all blocks stage Wd1^T (L2-served, tiny)
  for (int idx = tid; idx < H_*E_; idx += 256){
    int k = idx >> 7, e = idx & 127;
    t_l[e*65 + k] = Wd1[idx];
  }

  if (row < 64){
    if (tid < E_){
      const int e = tid;
      float s = pos_coords[row*3+0] * Wp[e*3+0];
      s = fmaf(pos_coords[row*3+1], Wp[e*3+1], s);
      s = fmaf(pos_coords[row*3+2], Wp[e*3+2], s);
      const float pe = s + bp[e];
      g_pe[row*E_ + e] = pe;
      pe_l[e] = pe;
    }
    __syncthreads();

    if (row == 0){
      for (int idx = tid; idx < E_*H_; idx += 256){
        int e = idx >> 6, k = idx & 63;
        g_wd1t[idx] = t_l[e*65 + k];
      }
    }
    if (tid < H_){
      const int k = tid;
      float s = 0.f;
      for (int e = 0; e < 128; ++e)
        s = fmaf(pe_l[e], t_l[e*65 + k], s);
      g_v1[row*H_ + k] = s + bd1[k];
    }
    return;
  }

  // ---- block 64: folded weights ----
  // W2eff[e][j] = W2[e][j] + 0.25 * sum_r B2[e][r]*A2[r][j]
  for (int idx = tid; idx < E_*H_; idx += 256){
    const int e = idx >> 6, j = idx & 63;
    float l = B2[e*4+0] * A2[0*64+j];
    l = fmaf(B2[e*4+1], A2[1*64+j], l);
    l = fmaf(B2[e*4+2], A2[2*64+j], l);
    l = fmaf(B2[e*4+3], A2[3*64+j], l);
    const float v = fmaf(0.25f, l, W2[idx]);
    w2_l[e*65 + j] = v;
    g_w2eff[idx] = v;
  }
  // W1eff[k][c] = W1[k][c] + 0.25 * sum_r B1[k][r]*A1[r][c]
  if (tid < H_*3){
    const int k = tid / 3, c = tid % 3;
    float l = B1[k*4+0] * A1[0*3+c];
    l = fmaf(B1[k*4+1], A1[1*3+c], l);
    l = fmaf(B1[k*4+2], A1[2*3+c], l);
    l = fmaf(B1[k*4+3], A1[3*3+c], l);
    g_w1eff[tid] = fmaf(0.25f, l, W1[tid]);
  }
  __syncthreads();

  // Meff[j][k] = sum_e W2eff[e][j] * Wd1t[e][k]   (64x64, 128-deep)
  {
    const int j  = tid >> 2;           // 0..63
    const int kq = tid & 3;            // k quarter
    float acc[16];
    #pragma unroll
    for (int kk = 0; kk < 16; ++kk) acc[kk] = 0.f;
    for (int e = 0; e < E_; ++e){
      const float w = w2_l[e*65 + j];
      #pragma unroll
      for (int kk = 0; kk < 16; ++kk)
        acc[kk] = fmaf(w, t_l[e*65 + kq*16 + kk], acc[kk]);
    }
    #pragma unroll
    for (int kk = 0; kk < 16; ++kk)
      g_meff[j*64 + kq*16 + kk] = acc[kk];
  }
}

// ---------------- K1: FUSED encoder (folded weights) -------------------------
// 256 blocks x 512 threads. t1 = relu(x @ W1eff) per lane (256 FMA).
// Phase A: wave w computes pf[e] for e in [w*16,+16) from W2eff (LDS bcast).
// Phase B: wave w computes u[k] for k in [w*8,+8) as t1 @ Meff (64-deep,
//          t1 stays in registers -- no pf_l round trip).
// Phase C: fused initial decode + ballot (unchanged).
// LDS ~98 KB -> 1 block/CU (same occupancy as before, 35% fewer VALU ops).
__global__ void __launch_bounds__(512) enc_kernel(
    const float* __restrict__ points,
    const float* __restrict__ Wd2, const float* __restrict__ bd2,
    float* __restrict__ out_pf)
{
  __shared__ float pf_l[E_*65];      // [e][point]: 33.3 KB
  __shared__ float u_l [64*65];      // [point][k]: 16.6 KB
  __shared__ float w2_l[E_*H_];      // W2eff [e][j]: 32 KB
  __shared__ float me_l[H_*H_];      // Meff  [j][k]: 16 KB
  const int tid  = threadIdx.x;
  const int w_u  = __builtin_amdgcn_readfirstlane(tid >> 6);  // 0..7
  const int lane = tid & 63;
  const int p0   = blockIdx.x * 64;
  const int p    = p0 + lane;
  const int b    = blockIdx.x >> 7;

  // cooperative weight staging (coalesced); overlaps with t1 compute below
  for (int idx = tid; idx < E_*H_; idx += 512) w2_l[idx] = g_w2eff[idx];
  for (int idx = tid; idx < H_*H_; idx += 512) me_l[idx] = g_meff[idx];

  const float x0 = points[p*3+0];
  const float x1 = points[p*3+1];
  const float x2 = points[p*3+2];

  float t1[64];
  #pragma unroll
  for (int k = 0; k < 64; ++k){
    float s = x0 * g_w1eff[k*3+0];           // wave-uniform -> s_load
    s = fmaf(x1, g_w1eff[k*3+1], s);
    s = fmaf(x2, g_w1eff[k*3+2], s);
    t1[k] = fmaxf(s, 0.0f);
  }
  __syncthreads();                   // w2_l/me_l ready

  // phase A: pf for this wave's 16 e; W2eff row from LDS (broadcast float4)
  const int e0 = w_u * 16;
  for (int ei = 0; ei < 16; ++ei){
    const int e = e0 + ei;
    const float4* w2row = (const float4*)(w2_l + e*64);   // 16B-aligned
    float s1 = 0.f;
    #pragma unroll
    for (int j4 = 0; j4 < 16; ++j4){
      const float4 w = w2row[j4];
      s1 = fmaf(t1[j4*4+0], w.x, s1);
      s1 = fmaf(t1[j4*4+1], w.y, s1);
      s1 = fmaf(t1[j4*4+2], w.z, s1);
      s1 = fmaf(t1[j4*4+3], w.w, s1);
    }
    pf_l[e*65 + lane] = s1;          // conflict-free
  }

  // phase B: u[kbase..kbase+8) = t1 @ Meff (64-deep, t1 in registers)
  const int kbase = w_u * 8;
  float uacc[8];
  #pragma unroll
  for (int kk = 0; kk < 8; ++kk) uacc[kk] = 0.f;
  #pragma unroll 4
  for (int j = 0; j < 64; ++j){
    const float t = t1[j];
    const float4 m0 = *(const float4*)(me_l + j*64 + kbase);      // bcast
    const float4 m1 = *(const float4*)(me_l + j*64 + kbase + 4);
    uacc[0] = fmaf(t, m0.x, uacc[0]);
    uacc[1] = fmaf(t, m0.y, uacc[1]);
    uacc[2] = fmaf(t, m0.z, uacc[2]);
    uacc[3] = fmaf(t, m0.w, uacc[3]);
    uacc[4] = fmaf(t, m1.x, uacc[4]);
    uacc[5] = fmaf(t, m1.y, uacc[5]);
    uacc[6] = fmaf(t, m1.z, uacc[6]);
    uacc[7] = fmaf(t, m1.w, uacc[7]);
  }
  #pragma unroll
  for (int kk = 0; kk < 8; ++kk){
    g_u[(size_t)(kbase + kk) * BN_ + p] = uacc[kk];   // coalesced
    u_l[lane*65 + kbase + kk] = uacc[kk];             // conflict-free
  }
  __syncthreads();                   // pf_l + u_l ready

  // coalesced pf store
  for (int idx = tid; idx < 64*E_; idx += 512){
    const int pt = idx >> 7, e = idx & 127;
    out_pf[(size_t)p0 * E_ + idx] = pf_l[e*65 + pt];
  }

  // fused initial decode + ballot: wave w handles i in [w*4, w*4+4)
  const float bd2v = bd2[0];
  float acc[4];
  #pragma unroll
  for (int ii = 0; ii < 4; ++ii) acc[ii] = 0.f;
  const int ibase = w_u * 4;
  const float* v = g_v1 + ((b * I_ + ibase) << 6);
  for (int k = 0; k < 64; ++k){
    const float wd2k = Wd2[k];
    const float uk = u_l[lane*65 + k];
    #pragma unroll
    for (int ii = 0; ii < 4; ++ii)
      acc[ii] = fmaf(wd2k, fmaxf(uk + v[ii*64 + k], 0.0f), acc[ii]);
  }
  #pragma unroll
  for (int ii = 0; ii < 4; ++ii){
    const int i = ibase + ii;
    u64 bal = __ballot(acc[ii] + bd2v > 0.0f);
    if (lane == 0) g_masks[(size_t)(b * I_ + i) * NW_ + (blockIdx.x & 127)] = bal;
  }
}

// ---------------- K2: FUSED inter + Gumbel-max + delta + v2 (16 blocks) -------
__global__ void __launch_bounds__(256) sample_kernel(
    const float* __restrict__ pos_coords,
    const float* __restrict__ Wp, const float* __restrict__ bp,
    const float* __restrict__ bd1)
{
  __shared__ int   inter_l[4*32];    // inter of this block's 4 rows vs all j
  __shared__ int   msum_l[32];       // popcount of each mask row of this b
  __shared__ float delta_l[4*E_];
  __shared__ float nc_l[4][3];
  const int tid  = threadIdx.x;
  const int row0 = blockIdx.x * 4;           // 4 rows, same b (32%4==0)
  const int b    = row0 >> 5;

  // pair popcounts: 128 (rl,j) pairs x 2 threads (64 words each)
  {
    const int pair = tid >> 1;               // 0..127
    const int rl   = pair >> 5;              // 0..3
    const int j    = pair & 31;
    const int half = tid & 1;
    const u64* mi = g_masks + (size_t)(row0 + rl) * NW_ + half*64;
    const u64* mj = g_masks + (size_t)(b*32 + j)  * NW_ + half*64;
    int s = 0;
    #pragma unroll
    for (int w = 0; w < 64; ++w) s += __popcll(mi[w] & mj[w]);
    s += __shfl_xor(s, 1, 64);
    if (half == 0) inter_l[pair] = s;
  }
  // diag popcounts (msum): 32 j x 8 threads (16 words each)
  {
    const int j  = tid >> 3;                 // 0..31
    const int ws = (tid & 7) * 16;
    const u64* mj = g_masks + (size_t)(b*32 + j) * NW_;
    int s = 0;
    #pragma unroll
    for (int w = 0; w < 16; ++w) s += __popcll(mj[ws + w]);
    s += __shfl_xor(s, 1, 64);
    s += __shfl_xor(s, 2, 64);
    s += __shfl_xor(s, 4, 64);
    if ((tid & 7) == 0) msum_l[j] = s;
  }
  __syncthreads();

  if (tid < 4){
    const int row = row0 + tid;              // = b*32 + i
    const int i = row & 31;
    const int msum_i = msum_l[i];
    float best = -INFINITY; int bestj = 0; bool any = false;
    for (int j = 0; j < 32; ++j){
      const int inter = inter_l[(tid << 5) + j];
      const int uni   = msum_i + msum_l[j] - inter;
      // EXACT f32 mimicry of the reference: inter/(union+1e-6) in f32.
      const float iou = (float)inter / ((float)uni + 1e-6f);
      const bool cand = (j != i) && (iou >= 0.1f);
      if (cand){
        any = true;
        const float uu = jax_uniform_2048((row << 5) + j);
        const float g  = -logf(-logf(uu));
        if (g > best){ best = g; bestj = j; }            // first-max like argmax
      }
    }
    nc_l[tid][0] = any ? pos_coords[(b*32 + bestj)*3 + 0] : 0.f;
    nc_l[tid][1] = any ? pos_coords[(b*32 + bestj)*3 + 1] : 0.f;
    nc_l[tid][2] = any ? pos_coords[(b*32 + bestj)*3 + 2] : 0.f;
  }
  __syncthreads();

  for (int idx = tid; idx < 4*E_; idx += 256){
    const int rl = idx >> 7, e = idx & 127;
    float ne = nc_l[rl][0] * Wp[e*3+0];
    ne = fmaf(nc_l[rl][1], Wp[e*3+1], ne);
    ne = fmaf(nc_l[rl][2], Wp[e*3+2], ne);
    ne = ne + bp[e];                                     // == bp when invalid
    delta_l[idx] = g_pe[(row0 + rl)*E_ + e] - ne;
  }
  __syncthreads();

  {
    const int rl = tid >> 6, k = tid & 63;
    float s = 0.f;
    for (int e = 0; e < 128; ++e)
      s = fmaf(delta_l[rl*E_ + e], g_wd1t[e*64 + k], s);
    g_v2[(row0 + rl)*H_ + k] = s + bd1[k];
  }
}

// ---------------- K3: refined decode (256 blocks x 1024 thr, LDS-staged u) ----
__global__ void __launch_bounds__(1024) dec_kernel(
    const float* __restrict__ Wd2, const float* __restrict__ bd2,
    float* __restrict__ out0)
{
  __shared__ float u_l[64*65];       // [point][k]: 16.6 KB
  const int tid  = threadIdx.x;
  const int w_u  = __builtin_amdgcn_readfirstlane(tid >> 6);  // 0..15
  const int lane = tid & 63;
  const int bc   = blockIdx.x;           // 256 blocks
  const int b    = bc >> 7;
  const int nb   = (bc & 127) << 6;
  const int n    = nb + lane;

  for (int idx = tid; idx < 64*64; idx += 1024){
    const int k = idx >> 6, pl = idx & 63;   // lanes: pl consecutive
    u_l[pl*65 + k] = g_u[(size_t)k * BN_ + b * N_ + nb + pl];
  }
  __syncthreads();

  const float bd2v = bd2[0];
  float acc[2];
  acc[0] = 0.f; acc[1] = 0.f;
  const int ibase = w_u * 2;
  const float* v = g_v2 + ((b * I_ + ibase) << 6);
  for (int k = 0; k < 64; ++k){
    const float wd2k = Wd2[k];
    const float uk = u_l[lane*65 + k];
    acc[0] = fmaf(wd2k, fmaxf(uk + v[k],      0.0f), acc[0]);
    acc[1] = fmaf(wd2k, fmaxf(uk + v[64 + k], 0.0f), acc[1]);
  }
  #pragma unroll
  for (int ii = 0; ii < 2; ++ii){
    const int i = ibase + ii;
    out0[(size_t)(b * I_ + i) * N_ + n] = acc[ii] + bd2v;
  }
}

// ---------------- launch ----------------
extern "C" void kernel_launch(void* const* d_in, const int* in_sizes, int n_in,
                              void* d_out, int out_size, void* d_ws, size_t ws_size,
                              hipStream_t stream)
{
  (void)in_sizes; (void)n_in; (void)out_size; (void)d_ws; (void)ws_size;
  const float* points     = (const float*)d_in[0];
  const float* pos_coords = (const float*)d_in[1];
  const float* W1  = (const float*)d_in[2];
  const float* A1  = (const float*)d_in[3];
  const float* B1  = (const float*)d_in[4];
  const float* W2  = (const float*)d_in[5];
  const float* A2  = (const float*)d_in[6];
  const float* B2  = (const float*)d_in[7];
  const float* Wp  = (const float*)d_in[8];
  const float* bp  = (const float*)d_in[9];
  const float* Wd1 = (const float*)d_in[10];
  const float* bd1 = (const float*)d_in[11];
  const float* Wd2 = (const float*)d_in[12];
  const float* bd2 = (const float*)d_in[13];

  float* out0   = (float*)d_out;                        // refined_logits [B,I,N]
  float* out_pf = out0 + (size_t)B_ * I_ * N_;          // point_feats   [B,N,E]

  prep_kernel<<<65, 256, 0, stream>>>(pos_coords, Wp, bp, Wd1, bd1,
                                      W1, A1, B1, W2, A2, B2);
  enc_kernel<<<256, 512, 0, stream>>>(points, Wd2, bd2, out_pf);
  sample_kernel<<<16, 256, 0, stream>>>(pos_coords, Wp, bp, bd1);
  dec_kernel<<<256, 1024, 0, stream>>>(Wd2, bd2, out0);
}